// Round 1
// baseline (264.365 us; speedup 1.0000x reference)
//
#include <hip/hip_runtime.h>

// XOR chain = inclusive prefix-XOR along axis 0 of [S=4096, B=8192] int32.
// 3-phase chunked scan: chunk totals -> exclusive chunk prefixes -> local scan.

#define S 4096
#define B 8192
#define B4 (B / 4)            // uint4 column-groups per row = 2048
#define CHUNK 64              // rows per chunk
#define NCHUNK (S / CHUNK)    // 64 chunks
#define TPB 256
#define NCOLTILE (B4 / TPB)   // 8 column tiles

__device__ __forceinline__ uint4 xor4(uint4 a, uint4 b) {
    a.x ^= b.x; a.y ^= b.y; a.z ^= b.z; a.w ^= b.w;
    return a;
}

// K1: ws[chunk][colg] = XOR of input rows in chunk, per uint4 column-group.
__global__ __launch_bounds__(TPB) void xor_chunk_total(
        const uint4* __restrict__ in, uint4* __restrict__ ws) {
    const int colg  = blockIdx.x * TPB + threadIdx.x;   // 0..B4-1
    const int chunk = blockIdx.y;
    const uint4* p = in + (size_t)chunk * CHUNK * B4 + colg;
    uint4 acc = make_uint4(0u, 0u, 0u, 0u);
#pragma unroll 8
    for (int r = 0; r < CHUNK; ++r) {
        acc = xor4(acc, p[(size_t)r * B4]);
    }
    ws[(size_t)chunk * B4 + colg] = acc;
}

// K2: in-place exclusive prefix-XOR over chunks for each column-group.
__global__ __launch_bounds__(TPB) void xor_prefix_chunks(uint4* __restrict__ ws) {
    const int colg = blockIdx.x * TPB + threadIdx.x;
    uint4 acc = make_uint4(0u, 0u, 0u, 0u);
#pragma unroll 4
    for (int c = 0; c < NCHUNK; ++c) {
        uint4* p = ws + (size_t)c * B4 + colg;
        uint4 t = *p;
        *p = acc;
        acc = xor4(acc, t);
    }
}

// K3: seed with exclusive chunk prefix, local inclusive scan, write output.
__global__ __launch_bounds__(TPB) void xor_scan_out(
        const uint4* __restrict__ in, const uint4* __restrict__ ws,
        uint4* __restrict__ out) {
    const int colg  = blockIdx.x * TPB + threadIdx.x;
    const int chunk = blockIdx.y;
    uint4 acc = ws[(size_t)chunk * B4 + colg];
    const uint4* p = in  + (size_t)chunk * CHUNK * B4 + colg;
    uint4*       q = out + (size_t)chunk * CHUNK * B4 + colg;
#pragma unroll 8
    for (int r = 0; r < CHUNK; ++r) {
        acc = xor4(acc, p[(size_t)r * B4]);
        q[(size_t)r * B4] = acc;
    }
}

extern "C" void kernel_launch(void* const* d_in, const int* in_sizes, int n_in,
                              void* d_out, int out_size, void* d_ws, size_t ws_size,
                              hipStream_t stream) {
    const uint4* in = (const uint4*)d_in[0];
    uint4* out = (uint4*)d_out;
    uint4* ws  = (uint4*)d_ws;   // needs NCHUNK * B * 4 = 2 MiB

    dim3 grid1(NCOLTILE, NCHUNK);
    dim3 grid2(NCOLTILE);
    xor_chunk_total<<<grid1, TPB, 0, stream>>>(in, ws);
    xor_prefix_chunks<<<grid2, TPB, 0, stream>>>(ws);
    xor_scan_out<<<grid1, TPB, 0, stream>>>(in, ws, out);
}

// Round 2
// 255.710 us; speedup vs baseline: 1.0338x; 1.0338x over previous
//
#include <hip/hip_runtime.h>

// XOR chain = inclusive prefix-XOR along axis 0 of [S=4096, B=8192] int32.
// 3-phase chunked scan: chunk totals -> exclusive chunk prefixes -> local scan.
// Round 2: NCHUNK 64->128 (2x waves/MLP), register-batched K2, nontemporal K3.

#define S 4096
#define B 8192
#define B4 (B / 4)            // uint4 column-groups per row = 2048
#define CHUNK 32              // rows per chunk
#define NCHUNK (S / CHUNK)    // 128 chunks
#define TPB 256
#define NCOLTILE (B4 / TPB)   // 8 column tiles

typedef unsigned int v4u __attribute__((ext_vector_type(4)));

// K1: ws[chunk][colg] = XOR of input rows in chunk, per uint4 column-group.
__global__ __launch_bounds__(TPB) void xor_chunk_total(
        const v4u* __restrict__ in, v4u* __restrict__ ws) {
    const int colg  = blockIdx.x * TPB + threadIdx.x;   // 0..B4-1
    const int chunk = blockIdx.y;
    const v4u* p = in + (size_t)chunk * CHUNK * B4 + colg;
    v4u acc = (v4u){0u, 0u, 0u, 0u};
#pragma unroll 16
    for (int r = 0; r < CHUNK; ++r) {
        acc ^= p[(size_t)r * B4];
    }
    ws[(size_t)chunk * B4 + colg] = acc;
}

// K2: in-place exclusive prefix-XOR over chunks for each column-group.
// One thread per column-group; batches of 8 independent loads -> 16 round
// trips instead of 128 serialized ones.
#define K2_TPB 64
__global__ __launch_bounds__(K2_TPB) void xor_prefix_chunks(v4u* __restrict__ ws) {
    const int colg = blockIdx.x * K2_TPB + threadIdx.x;  // 0..B4-1
    v4u acc = (v4u){0u, 0u, 0u, 0u};
    for (int b = 0; b < NCHUNK / 8; ++b) {
        v4u vals[8];
#pragma unroll
        for (int j = 0; j < 8; ++j) {
            vals[j] = ws[(size_t)(b * 8 + j) * B4 + colg];
        }
#pragma unroll
        for (int j = 0; j < 8; ++j) {
            v4u t = vals[j];
            ws[(size_t)(b * 8 + j) * B4 + colg] = acc;
            acc ^= t;
        }
    }
}

// K3: seed with exclusive chunk prefix, local inclusive scan, write output.
// Nontemporal input loads (last use) + nontemporal output stores (no reuse)
// keep the LLC copy of the input warm for this kernel's own reads.
__global__ __launch_bounds__(TPB) void xor_scan_out(
        const v4u* __restrict__ in, const v4u* __restrict__ ws,
        v4u* __restrict__ out) {
    const int colg  = blockIdx.x * TPB + threadIdx.x;
    const int chunk = blockIdx.y;
    v4u acc = ws[(size_t)chunk * B4 + colg];
    const v4u* p = in  + (size_t)chunk * CHUNK * B4 + colg;
    v4u*       q = out + (size_t)chunk * CHUNK * B4 + colg;
#pragma unroll 16
    for (int r = 0; r < CHUNK; ++r) {
        acc ^= __builtin_nontemporal_load(&p[(size_t)r * B4]);
        __builtin_nontemporal_store(acc, &q[(size_t)r * B4]);
    }
}

extern "C" void kernel_launch(void* const* d_in, const int* in_sizes, int n_in,
                              void* d_out, int out_size, void* d_ws, size_t ws_size,
                              hipStream_t stream) {
    const v4u* in = (const v4u*)d_in[0];
    v4u* out = (v4u*)d_out;
    v4u* ws  = (v4u*)d_ws;   // needs NCHUNK * B4 * 16 = 4 MiB

    dim3 grid1(NCOLTILE, NCHUNK);
    dim3 grid2(B4 / K2_TPB);
    xor_chunk_total<<<grid1, TPB, 0, stream>>>(in, ws);
    xor_prefix_chunks<<<grid2, K2_TPB, 0, stream>>>(ws);
    xor_scan_out<<<grid1, TPB, 0, stream>>>(in, ws, out);
}